// Round 3
// baseline (190.183 us; speedup 1.0000x reference)
//
#include <hip/hip_runtime.h>
#include <hip/hip_bf16.h>

#define BATCH 4
#define SEQ   4096
#define DIN   768
#define DOUT  64

typedef __attribute__((ext_vector_type(4))) float f32x4;
typedef __attribute__((ext_vector_type(8))) short short8;

#define QSCALE 0.18033688011112043f  /* 0.125 * log2(e) */

static __device__ __forceinline__ unsigned short f2bf(float f) {
    union { float f; unsigned u; } un; un.f = f;
    unsigned r = un.u + 0x7FFF + ((un.u >> 16) & 1);
    return (unsigned short)(r >> 16);
}

// ---------------------------------------------------------------------------
// Kernel 0: transpose+convert weights: wT[o][n][k] = bf16(w_o[k][n])
// grid = 36 blocks (3 o x 12 k-tiles), 256 threads
// ---------------------------------------------------------------------------
__global__ void wprep_kernel(const float* __restrict__ wq,
                             const float* __restrict__ wk,
                             const float* __restrict__ wv,
                             unsigned short* __restrict__ wT) {
    __shared__ float lds[64][65];
    int o = blockIdx.x / 12, kt = blockIdx.x % 12;
    const float* w = (o == 0) ? wq : (o == 1) ? wk : wv;
    int t = threadIdx.x;
    int k0 = kt * 64;
    #pragma unroll
    for (int i = 0; i < 16; ++i) {
        int flat = t + i * 256;
        int kl = flat >> 6, n = flat & 63;
        lds[kl][n] = w[(k0 + kl) * 64 + n];
    }
    __syncthreads();
    #pragma unroll
    for (int i = 0; i < 16; ++i) {
        int flat = t + i * 256;
        int n = flat >> 6, c = flat & 63;
        wT[(o * 64 + n) * 768 + k0 + c] = f2bf(lds[c][n]);
    }
}

// ---------------------------------------------------------------------------
// Kernel 1: QKV projection. 1 wave per block, 32 rows per wave.
// grid = 16384/32 = 512 blocks x 64 threads.
// Q pre-scaled by 0.125*log2e; V stored transposed as VT[b][64][4096].
// ---------------------------------------------------------------------------
__global__ void __launch_bounds__(64) proj_kernel(
        const float* __restrict__ x,
        const float* __restrict__ bq,
        const float* __restrict__ bk,
        const float* __restrict__ bv,
        const unsigned short* __restrict__ wT,
        unsigned short* __restrict__ Qo,
        unsigned short* __restrict__ Ko,
        unsigned short* __restrict__ VTo) {
    int lane = threadIdx.x;
    int m = lane & 15, g = lane >> 4;
    int r0 = blockIdx.x * 32;

    f32x4 acc[2][3][4];
    #pragma unroll
    for (int st = 0; st < 2; ++st)
        #pragma unroll
        for (int o = 0; o < 3; ++o)
            #pragma unroll
            for (int t = 0; t < 4; ++t)
                acc[st][o][t] = (f32x4){0.f, 0.f, 0.f, 0.f};

    for (int kc = 0; kc < 24; ++kc) {
        int k0 = kc * 32 + g * 8;
        short8 a[2];
        #pragma unroll
        for (int st = 0; st < 2; ++st) {
            const float* xp = x + (size_t)(r0 + st * 16 + m) * DIN + k0;
            float4 lo = *(const float4*)xp;
            float4 hi = *(const float4*)(xp + 4);
            short8 av;
            av[0] = (short)f2bf(lo.x); av[1] = (short)f2bf(lo.y);
            av[2] = (short)f2bf(lo.z); av[3] = (short)f2bf(lo.w);
            av[4] = (short)f2bf(hi.x); av[5] = (short)f2bf(hi.y);
            av[6] = (short)f2bf(hi.z); av[7] = (short)f2bf(hi.w);
            a[st] = av;
        }
        #pragma unroll
        for (int o = 0; o < 3; ++o) {
            #pragma unroll
            for (int t = 0; t < 4; ++t) {
                short8 bfrg = *(const short8*)(wT + (size_t)(o * 64 + t * 16 + m) * DIN + k0);
                acc[0][o][t] = __builtin_amdgcn_mfma_f32_16x16x32_bf16(a[0], bfrg, acc[0][o][t], 0, 0, 0);
                acc[1][o][t] = __builtin_amdgcn_mfma_f32_16x16x32_bf16(a[1], bfrg, acc[1][o][t], 0, 0, 0);
            }
        }
    }

    #pragma unroll
    for (int o = 0; o < 3; ++o) {
        const float* bias_p = (o == 0) ? bq : (o == 1) ? bk : bv;
        #pragma unroll
        for (int t = 0; t < 4; ++t) {
            float bias = bias_p[t * 16 + m];
            #pragma unroll
            for (int st = 0; st < 2; ++st) {
                #pragma unroll
                for (int r = 0; r < 4; ++r) {
                    int row = r0 + st * 16 + g * 4 + r;
                    float val = acc[st][o][t][r] + bias;
                    if (o == 0) {
                        Qo[row * 64 + t * 16 + m] = f2bf(val * QSCALE);
                    } else if (o == 1) {
                        Ko[row * 64 + t * 16 + m] = f2bf(val);
                    } else {
                        int bb = row >> 12, ss = row & 4095;
                        VTo[(size_t)(bb * 64 + t * 16 + m) * SEQ + ss] = f2bf(val);
                    }
                }
            }
        }
    }
}

// ---------------------------------------------------------------------------
// Kernel 2: causal flash attention. 1 wave per block, 16 q rows per wave.
// grid = 4*256 = 1024 blocks x 64 threads, longest q-tiles dispatched first.
// ---------------------------------------------------------------------------
__global__ void __launch_bounds__(64) attn_kernel(
        const unsigned short* __restrict__ Q,
        const unsigned short* __restrict__ K,
        const unsigned short* __restrict__ VT,
        float* __restrict__ out) {
    __shared__ __align__(16) unsigned short P_lds[16 * 40];

    int idx = blockIdx.x;
    int qt = 255 - (idx >> 2);
    int b = idx & 3;
    int q0 = qt * 16;
    int lane = threadIdx.x;
    int m = lane & 15, g = lane >> 4;

    const unsigned short* Qb = Q + (size_t)(b * SEQ + q0 + m) * DOUT + g * 8;
    short8 qf0 = *(const short8*)(Qb);
    short8 qf1 = *(const short8*)(Qb + 32);

    f32x4 acc[4];
    #pragma unroll
    for (int t = 0; t < 4; ++t) acc[t] = (f32x4){0.f, 0.f, 0.f, 0.f};
    float mrun[4], lrun[4];
    #pragma unroll
    for (int r = 0; r < 4; ++r) { mrun[r] = -INFINITY; lrun[r] = 0.f; }

    int nsteps = (q0 + 47) >> 5;
    const unsigned short* Kb = K + (size_t)(b * SEQ) * DOUT;
    const unsigned short* Vb = VT + (size_t)(b * DOUT) * SEQ;

    for (int s = 0; s < nsteps; ++s) {
        int kv0 = s * 32;
        f32x4 sc[2];
        sc[0] = (f32x4){0.f, 0.f, 0.f, 0.f};
        sc[1] = (f32x4){0.f, 0.f, 0.f, 0.f};
        #pragma unroll
        for (int tt = 0; tt < 2; ++tt) {
            const unsigned short* kp = Kb + (size_t)(kv0 + tt * 16 + m) * DOUT + g * 8;
            short8 kf0 = *(const short8*)(kp);
            short8 kf1 = *(const short8*)(kp + 32);
            sc[tt] = __builtin_amdgcn_mfma_f32_16x16x32_bf16(qf0, kf0, sc[tt], 0, 0, 0);
            sc[tt] = __builtin_amdgcn_mfma_f32_16x16x32_bf16(qf1, kf1, sc[tt], 0, 0, 0);
        }
        if (s == nsteps - 1) {
            // causal mask on the diagonal tiles: keep kv <= q
            #pragma unroll
            for (int tt = 0; tt < 2; ++tt)
                #pragma unroll
                for (int r = 0; r < 4; ++r)
                    if (kv0 + tt * 16 + m > q0 + g * 4 + r) sc[tt][r] = -INFINITY;
        }
        float rmax[4], rsum[4];
        float pv[2][4];
        #pragma unroll
        for (int r = 0; r < 4; ++r) rmax[r] = fmaxf(sc[0][r], sc[1][r]);
        #pragma unroll
        for (int msk = 1; msk <= 8; msk <<= 1)
            #pragma unroll
            for (int r = 0; r < 4; ++r)
                rmax[r] = fmaxf(rmax[r], __shfl_xor(rmax[r], msk));
        #pragma unroll
        for (int r = 0; r < 4; ++r) {
            float mnew = fmaxf(mrun[r], rmax[r]);
            float alpha = exp2f(mrun[r] - mnew);  // -inf - finite -> 0 on first step
            mrun[r] = mnew;
            float p0 = exp2f(sc[0][r] - mnew);
            float p1 = exp2f(sc[1][r] - mnew);
            pv[0][r] = p0; pv[1][r] = p1;
            rsum[r] = p0 + p1;
            lrun[r] *= alpha;
            #pragma unroll
            for (int t = 0; t < 4; ++t) acc[t][r] *= alpha;  // per-row rescale (FIXED)
        }
        #pragma unroll
        for (int msk = 1; msk <= 8; msk <<= 1)
            #pragma unroll
            for (int r = 0; r < 4; ++r)
                rsum[r] += __shfl_xor(rsum[r], msk);
        #pragma unroll
        for (int r = 0; r < 4; ++r) lrun[r] += rsum[r];

        // P -> LDS (bf16), read back as A-fragment
        #pragma unroll
        for (int tt = 0; tt < 2; ++tt)
            #pragma unroll
            for (int r = 0; r < 4; ++r)
                P_lds[(g * 4 + r) * 40 + tt * 16 + m] = f2bf(pv[tt][r]);
        short8 pa = *(const short8*)&P_lds[m * 40 + g * 8];

        #pragma unroll
        for (int t = 0; t < 4; ++t) {
            short8 vf = *(const short8*)(Vb + (size_t)(t * 16 + m) * SEQ + kv0 + g * 8);
            acc[t] = __builtin_amdgcn_mfma_f32_16x16x32_bf16(pa, vf, acc[t], 0, 0, 0);
        }
    }

    float inv[4];
    #pragma unroll
    for (int r = 0; r < 4; ++r) inv[r] = 1.0f / lrun[r];
    #pragma unroll
    for (int t = 0; t < 4; ++t)
        #pragma unroll
        for (int r = 0; r < 4; ++r)
            out[(size_t)(b * SEQ + q0 + g * 4 + r) * DOUT + t * 16 + m] = acc[t][r] * inv[r];
}

// ---------------------------------------------------------------------------
extern "C" void kernel_launch(void* const* d_in, const int* in_sizes, int n_in,
                              void* d_out, int out_size, void* d_ws, size_t ws_size,
                              hipStream_t stream) {
    const float* x  = (const float*)d_in[0];
    const float* wq = (const float*)d_in[1];
    const float* bq = (const float*)d_in[2];
    const float* wk = (const float*)d_in[3];
    const float* bk = (const float*)d_in[4];
    const float* wv = (const float*)d_in[5];
    const float* bv = (const float*)d_in[6];
    float* out = (float*)d_out;

    char* ws = (char*)d_ws;
    unsigned short* wT = (unsigned short*)ws;                       // 294912 B
    unsigned short* Q  = (unsigned short*)(ws + 294912);            // 2 MB
    unsigned short* K  = (unsigned short*)(ws + 294912 + 2097152);  // 2 MB
    unsigned short* VT = (unsigned short*)(ws + 294912 + 4194304);  // 2 MB

    wprep_kernel<<<36, 256, 0, stream>>>(wq, wk, wv, wT);
    proj_kernel<<<512, 64, 0, stream>>>(x, bq, bk, bv, wT, Q, K, VT);
    attn_kernel<<<1024, 64, 0, stream>>>(Q, K, VT, out);
}

// Round 4
// 128.742 us; speedup vs baseline: 1.4772x; 1.4772x over previous
//
#include <hip/hip_runtime.h>
#include <hip/hip_bf16.h>

#define BATCH 4
#define SEQ   4096
#define DIN   768
#define DOUT  64

typedef __attribute__((ext_vector_type(4))) float f32x4;
typedef __attribute__((ext_vector_type(8))) short short8;

#define QSCALE 0.18033688011112043f  /* 0.125 * log2(e) */

static __device__ __forceinline__ unsigned short f2bf(float f) {
    union { float f; unsigned u; } un; un.f = f;
    unsigned r = un.u + 0x7FFF + ((un.u >> 16) & 1);
    return (unsigned short)(r >> 16);
}

// ---------------------------------------------------------------------------
// Kernel 0: transpose+convert weights: wT[o][n][k] = bf16(w_o[k][n])
// ---------------------------------------------------------------------------
__global__ void wprep_kernel(const float* __restrict__ wq,
                             const float* __restrict__ wk,
                             const float* __restrict__ wv,
                             unsigned short* __restrict__ wT) {
    __shared__ float lds[64][65];
    int o = blockIdx.x / 12, kt = blockIdx.x % 12;
    const float* w = (o == 0) ? wq : (o == 1) ? wk : wv;
    int t = threadIdx.x;
    int k0 = kt * 64;
    #pragma unroll
    for (int i = 0; i < 16; ++i) {
        int flat = t + i * 256;
        int kl = flat >> 6, n = flat & 63;
        lds[kl][n] = w[(k0 + kl) * 64 + n];
    }
    __syncthreads();
    #pragma unroll
    for (int i = 0; i < 16; ++i) {
        int flat = t + i * 256;
        int n = flat >> 6, c = flat & 63;
        wT[(o * 64 + n) * 768 + k0 + c] = f2bf(lds[c][n]);
    }
}

// ---------------------------------------------------------------------------
// Kernel 1: QKV projection, 4-way split-K.
// Block = 256 thr = 4 waves over one 16-row tile; wave w does k-chunks
// w, w+4, ... (6 of 24). Partials combined in LDS; wave 0 does epilogue.
// grid = 16384/16 = 1024 blocks.
// ---------------------------------------------------------------------------
__global__ void __launch_bounds__(256) proj_kernel(
        const float* __restrict__ x,
        const float* __restrict__ bq,
        const float* __restrict__ bk,
        const float* __restrict__ bv,
        const unsigned short* __restrict__ wT,
        unsigned short* __restrict__ Qo,
        unsigned short* __restrict__ Ko,
        unsigned short* __restrict__ VTo) {
    __shared__ float part[3][16][192];
    int tid = threadIdx.x;
    int wv = tid >> 6;
    int lane = tid & 63;
    int m = lane & 15, g = lane >> 4;
    int r0 = blockIdx.x * 16;

    f32x4 acc[3][4];
    #pragma unroll
    for (int o = 0; o < 3; ++o)
        #pragma unroll
        for (int t = 0; t < 4; ++t)
            acc[o][t] = (f32x4){0.f, 0.f, 0.f, 0.f};

    for (int i = 0; i < 6; ++i) {
        int kc = wv + i * 4;
        int k0 = kc * 32 + g * 8;
        const float* xp = x + (size_t)(r0 + m) * DIN + k0;
        float4 lo = *(const float4*)xp;
        float4 hi = *(const float4*)(xp + 4);
        short8 ah;
        ah[0] = (short)f2bf(lo.x); ah[1] = (short)f2bf(lo.y);
        ah[2] = (short)f2bf(lo.z); ah[3] = (short)f2bf(lo.w);
        ah[4] = (short)f2bf(hi.x); ah[5] = (short)f2bf(hi.y);
        ah[6] = (short)f2bf(hi.z); ah[7] = (short)f2bf(hi.w);
        #pragma unroll
        for (int o = 0; o < 3; ++o) {
            #pragma unroll
            for (int t = 0; t < 4; ++t) {
                short8 bfrg = *(const short8*)(wT + (size_t)(o * 64 + t * 16 + m) * DIN + k0);
                acc[o][t] = __builtin_amdgcn_mfma_f32_16x16x32_bf16(ah, bfrg, acc[o][t], 0, 0, 0);
            }
        }
    }

    if (wv > 0) {
        #pragma unroll
        for (int o = 0; o < 3; ++o)
            #pragma unroll
            for (int t = 0; t < 4; ++t)
                #pragma unroll
                for (int r = 0; r < 4; ++r)
                    part[wv - 1][g * 4 + r][o * 64 + t * 16 + m] = acc[o][t][r];
    }
    __syncthreads();
    if (wv == 0) {
        #pragma unroll
        for (int o = 0; o < 3; ++o)
            #pragma unroll
            for (int t = 0; t < 4; ++t)
                #pragma unroll
                for (int r = 0; r < 4; ++r)
                    acc[o][t][r] += part[0][g * 4 + r][o * 64 + t * 16 + m]
                                  + part[1][g * 4 + r][o * 64 + t * 16 + m]
                                  + part[2][g * 4 + r][o * 64 + t * 16 + m];
        #pragma unroll
        for (int o = 0; o < 3; ++o) {
            const float* bias_p = (o == 0) ? bq : (o == 1) ? bk : bv;
            #pragma unroll
            for (int t = 0; t < 4; ++t) {
                float bias = bias_p[t * 16 + m];
                #pragma unroll
                for (int r = 0; r < 4; ++r) {
                    int row = r0 + g * 4 + r;
                    float val = acc[o][t][r] + bias;
                    if (o == 0) {
                        Qo[row * 64 + t * 16 + m] = f2bf(val * QSCALE);
                    } else if (o == 1) {
                        Ko[row * 64 + t * 16 + m] = f2bf(val);
                    } else {
                        int bb = row >> 12, ss = row & 4095;
                        VTo[(size_t)(bb * 64 + t * 16 + m) * SEQ + ss] = f2bf(val);
                    }
                }
            }
        }
    }
}

// ---------------------------------------------------------------------------
// Kernel 2: causal flash attention with 8-way KV split per q-tile.
// Block = 512 thr = 8 waves; wave w does KV steps w, w+8, ... with its own
// online softmax; LDS combine at the end. K prefetched 1 step ahead; V
// loaded at top of step (hides under QK+softmax).
// grid = 4*256 = 1024 blocks, longest q-tiles first.
// ---------------------------------------------------------------------------
__global__ void __launch_bounds__(512) attn_kernel(
        const unsigned short* __restrict__ Q,
        const unsigned short* __restrict__ K,
        const unsigned short* __restrict__ VT,
        float* __restrict__ out) {
    __shared__ __align__(16) unsigned short P_lds[8][16 * 40];
    __shared__ __align__(16) float pacc[8][16][64];
    __shared__ float pm[8][16];
    __shared__ float pl[8][16];

    int idx = blockIdx.x;
    int qt = 255 - (idx >> 2);
    int b = idx & 3;
    int q0 = qt * 16;
    int tid = threadIdx.x;
    int w = tid >> 6;
    int lane = tid & 63;
    int m = lane & 15, g = lane >> 4;

    const unsigned short* Qb = Q + (size_t)(b * SEQ + q0 + m) * DOUT + g * 8;
    short8 qf0 = *(const short8*)(Qb);
    short8 qf1 = *(const short8*)(Qb + 32);

    f32x4 acc[4];
    #pragma unroll
    for (int t = 0; t < 4; ++t) acc[t] = (f32x4){0.f, 0.f, 0.f, 0.f};
    float mrun[4], lrun[4];
    #pragma unroll
    for (int r = 0; r < 4; ++r) { mrun[r] = -INFINITY; lrun[r] = 0.f; }

    int nsteps = (q0 + 47) >> 5;
    const unsigned short* Kb = K + (size_t)(b * SEQ) * DOUT;
    const unsigned short* Vb = VT + (size_t)(b * DOUT) * SEQ;

    short8 kcur[4];
    if (w < nsteps) {
        int kv0 = w * 32;
        #pragma unroll
        for (int tt = 0; tt < 2; ++tt) {
            const unsigned short* kp = Kb + (size_t)(kv0 + tt * 16 + m) * DOUT + g * 8;
            kcur[tt * 2 + 0] = *(const short8*)(kp);
            kcur[tt * 2 + 1] = *(const short8*)(kp + 32);
        }
    }

    for (int s = w; s < nsteps; s += 8) {
        int kv0 = s * 32;
        // V for current step (latency hides under QK + softmax)
        short8 vcur[4];
        #pragma unroll
        for (int t = 0; t < 4; ++t)
            vcur[t] = *(const short8*)(Vb + (size_t)(t * 16 + m) * SEQ + kv0 + g * 8);
        // K prefetch for next step of this wave
        short8 knxt[4];
        int sn = s + 8;
        if (sn < nsteps) {
            int kvn = sn * 32;
            #pragma unroll
            for (int tt = 0; tt < 2; ++tt) {
                const unsigned short* kp = Kb + (size_t)(kvn + tt * 16 + m) * DOUT + g * 8;
                knxt[tt * 2 + 0] = *(const short8*)(kp);
                knxt[tt * 2 + 1] = *(const short8*)(kp + 32);
            }
        }

        f32x4 sc[2];
        sc[0] = (f32x4){0.f, 0.f, 0.f, 0.f};
        sc[1] = (f32x4){0.f, 0.f, 0.f, 0.f};
        sc[0] = __builtin_amdgcn_mfma_f32_16x16x32_bf16(qf0, kcur[0], sc[0], 0, 0, 0);
        sc[0] = __builtin_amdgcn_mfma_f32_16x16x32_bf16(qf1, kcur[1], sc[0], 0, 0, 0);
        sc[1] = __builtin_amdgcn_mfma_f32_16x16x32_bf16(qf0, kcur[2], sc[1], 0, 0, 0);
        sc[1] = __builtin_amdgcn_mfma_f32_16x16x32_bf16(qf1, kcur[3], sc[1], 0, 0, 0);

        if (s == nsteps - 1) {
            #pragma unroll
            for (int tt = 0; tt < 2; ++tt)
                #pragma unroll
                for (int r = 0; r < 4; ++r)
                    if (kv0 + tt * 16 + m > q0 + g * 4 + r) sc[tt][r] = -INFINITY;
        }

        float rmax[4], rsum[4];
        float pv[2][4];
        #pragma unroll
        for (int r = 0; r < 4; ++r) rmax[r] = fmaxf(sc[0][r], sc[1][r]);
        #pragma unroll
        for (int msk = 1; msk <= 8; msk <<= 1)
            #pragma unroll
            for (int r = 0; r < 4; ++r)
                rmax[r] = fmaxf(rmax[r], __shfl_xor(rmax[r], msk));
        #pragma unroll
        for (int r = 0; r < 4; ++r) {
            float mnew = fmaxf(mrun[r], rmax[r]);
            float alpha = exp2f(mrun[r] - mnew);
            mrun[r] = mnew;
            float p0 = exp2f(sc[0][r] - mnew);
            float p1 = exp2f(sc[1][r] - mnew);
            pv[0][r] = p0; pv[1][r] = p1;
            rsum[r] = p0 + p1;
            lrun[r] *= alpha;
            #pragma unroll
            for (int t = 0; t < 4; ++t) acc[t][r] *= alpha;
        }
        #pragma unroll
        for (int msk = 1; msk <= 8; msk <<= 1)
            #pragma unroll
            for (int r = 0; r < 4; ++r)
                rsum[r] += __shfl_xor(rsum[r], msk);
        #pragma unroll
        for (int r = 0; r < 4; ++r) lrun[r] += rsum[r];

        #pragma unroll
        for (int tt = 0; tt < 2; ++tt)
            #pragma unroll
            for (int r = 0; r < 4; ++r)
                P_lds[w][(g * 4 + r) * 40 + tt * 16 + m] = f2bf(pv[tt][r]);
        short8 pa = *(const short8*)&P_lds[w][m * 40 + g * 8];

        #pragma unroll
        for (int t = 0; t < 4; ++t)
            acc[t] = __builtin_amdgcn_mfma_f32_16x16x32_bf16(pa, vcur[t], acc[t], 0, 0, 0);

        if (sn < nsteps) {
            #pragma unroll
            for (int tt = 0; tt < 4; ++tt) kcur[tt] = knxt[tt];
        }
    }

    // write per-wave partials
    if (m == 0) {
        #pragma unroll
        for (int r = 0; r < 4; ++r) {
            pm[w][g * 4 + r] = mrun[r];
            pl[w][g * 4 + r] = lrun[r];
        }
    }
    #pragma unroll
    for (int t = 0; t < 4; ++t)
        #pragma unroll
        for (int r = 0; r < 4; ++r)
            pacc[w][g * 4 + r][t * 16 + m] = acc[t][r];
    __syncthreads();

    // combine: threads 0..255 -> (row, col-quad)
    if (tid < 256) {
        int row = tid >> 4;
        int c4 = (tid & 15) * 4;
        float mmax = pm[0][row];
        #pragma unroll
        for (int w2 = 1; w2 < 8; ++w2) mmax = fmaxf(mmax, pm[w2][row]);
        float lt = 0.f;
        float o0 = 0.f, o1 = 0.f, o2 = 0.f, o3 = 0.f;
        #pragma unroll
        for (int w2 = 0; w2 < 8; ++w2) {
            float sc2 = exp2f(pm[w2][row] - mmax);
            lt += pl[w2][row] * sc2;
            const float4 pa4 = *(const float4*)&pacc[w2][row][c4];
            o0 += pa4.x * sc2; o1 += pa4.y * sc2;
            o2 += pa4.z * sc2; o3 += pa4.w * sc2;
        }
        float invl = 1.0f / lt;
        float4 res = make_float4(o0 * invl, o1 * invl, o2 * invl, o3 * invl);
        *(float4*)&out[(size_t)(b * SEQ + q0 + row) * DOUT + c4] = res;
    }
}

// ---------------------------------------------------------------------------
extern "C" void kernel_launch(void* const* d_in, const int* in_sizes, int n_in,
                              void* d_out, int out_size, void* d_ws, size_t ws_size,
                              hipStream_t stream) {
    const float* x  = (const float*)d_in[0];
    const float* wq = (const float*)d_in[1];
    const float* bq = (const float*)d_in[2];
    const float* wk = (const float*)d_in[3];
    const float* bk = (const float*)d_in[4];
    const float* wv = (const float*)d_in[5];
    const float* bv = (const float*)d_in[6];
    float* out = (float*)d_out;

    char* ws = (char*)d_ws;
    unsigned short* wT = (unsigned short*)ws;                       // 294912 B
    unsigned short* Q  = (unsigned short*)(ws + 294912);            // 2 MB
    unsigned short* K  = (unsigned short*)(ws + 294912 + 2097152);  // 2 MB
    unsigned short* VT = (unsigned short*)(ws + 294912 + 4194304);  // 2 MB

    wprep_kernel<<<36, 256, 0, stream>>>(wq, wk, wv, wT);
    proj_kernel<<<1024, 256, 0, stream>>>(x, bq, bk, bv, wT, Q, K, VT);
    attn_kernel<<<1024, 512, 0, stream>>>(Q, K, VT, out);
}

// Round 5
// 128.698 us; speedup vs baseline: 1.4778x; 1.0003x over previous
//
#include <hip/hip_runtime.h>
#include <hip/hip_bf16.h>

#define BATCH 4
#define SEQ   4096
#define DIN   768
#define DOUT  64

typedef __attribute__((ext_vector_type(4))) float f32x4;
typedef __attribute__((ext_vector_type(8))) short short8;

#define QSCALE 0.18033688011112043f  /* 0.125 * log2(e) */

static __device__ __forceinline__ unsigned short f2bf(float f) {
    union { float f; unsigned u; } un; un.f = f;
    unsigned r = un.u + 0x7FFF + ((un.u >> 16) & 1);
    return (unsigned short)(r >> 16);
}

// ---------------------------------------------------------------------------
// Kernel 0: transpose+convert weights: wT[o][n][k] = bf16(w_o[k][n])
// ---------------------------------------------------------------------------
__global__ void wprep_kernel(const float* __restrict__ wq,
                             const float* __restrict__ wk,
                             const float* __restrict__ wv,
                             unsigned short* __restrict__ wT) {
    __shared__ float lds[64][65];
    int o = blockIdx.x / 12, kt = blockIdx.x % 12;
    const float* w = (o == 0) ? wq : (o == 1) ? wk : wv;
    int t = threadIdx.x;
    int k0 = kt * 64;
    #pragma unroll
    for (int i = 0; i < 16; ++i) {
        int flat = t + i * 256;
        int kl = flat >> 6, n = flat & 63;
        lds[kl][n] = w[(k0 + kl) * 64 + n];
    }
    __syncthreads();
    #pragma unroll
    for (int i = 0; i < 16; ++i) {
        int flat = t + i * 256;
        int n = flat >> 6, c = flat & 63;
        wT[(o * 64 + n) * 768 + k0 + c] = f2bf(lds[c][n]);
    }
}

// ---------------------------------------------------------------------------
// Kernel 1: QKV projection, 4-way split-K. (unchanged this round)
// ---------------------------------------------------------------------------
__global__ void __launch_bounds__(256) proj_kernel(
        const float* __restrict__ x,
        const float* __restrict__ bq,
        const float* __restrict__ bk,
        const float* __restrict__ bv,
        const unsigned short* __restrict__ wT,
        unsigned short* __restrict__ Qo,
        unsigned short* __restrict__ Ko,
        unsigned short* __restrict__ VTo) {
    __shared__ float part[3][16][192];
    int tid = threadIdx.x;
    int wv = tid >> 6;
    int lane = tid & 63;
    int m = lane & 15, g = lane >> 4;
    int r0 = blockIdx.x * 16;

    f32x4 acc[3][4];
    #pragma unroll
    for (int o = 0; o < 3; ++o)
        #pragma unroll
        for (int t = 0; t < 4; ++t)
            acc[o][t] = (f32x4){0.f, 0.f, 0.f, 0.f};

    for (int i = 0; i < 6; ++i) {
        int kc = wv + i * 4;
        int k0 = kc * 32 + g * 8;
        const float* xp = x + (size_t)(r0 + m) * DIN + k0;
        float4 lo = *(const float4*)xp;
        float4 hi = *(const float4*)(xp + 4);
        short8 ah;
        ah[0] = (short)f2bf(lo.x); ah[1] = (short)f2bf(lo.y);
        ah[2] = (short)f2bf(lo.z); ah[3] = (short)f2bf(lo.w);
        ah[4] = (short)f2bf(hi.x); ah[5] = (short)f2bf(hi.y);
        ah[6] = (short)f2bf(hi.z); ah[7] = (short)f2bf(hi.w);
        #pragma unroll
        for (int o = 0; o < 3; ++o) {
            #pragma unroll
            for (int t = 0; t < 4; ++t) {
                short8 bfrg = *(const short8*)(wT + (size_t)(o * 64 + t * 16 + m) * DIN + k0);
                acc[o][t] = __builtin_amdgcn_mfma_f32_16x16x32_bf16(ah, bfrg, acc[o][t], 0, 0, 0);
            }
        }
    }

    if (wv > 0) {
        #pragma unroll
        for (int o = 0; o < 3; ++o)
            #pragma unroll
            for (int t = 0; t < 4; ++t)
                #pragma unroll
                for (int r = 0; r < 4; ++r)
                    part[wv - 1][g * 4 + r][o * 64 + t * 16 + m] = acc[o][t][r];
    }
    __syncthreads();
    if (wv == 0) {
        #pragma unroll
        for (int o = 0; o < 3; ++o)
            #pragma unroll
            for (int t = 0; t < 4; ++t)
                #pragma unroll
                for (int r = 0; r < 4; ++r)
                    acc[o][t][r] += part[0][g * 4 + r][o * 64 + t * 16 + m]
                                  + part[1][g * 4 + r][o * 64 + t * 16 + m]
                                  + part[2][g * 4 + r][o * 64 + t * 16 + m];
        #pragma unroll
        for (int o = 0; o < 3; ++o) {
            const float* bias_p = (o == 0) ? bq : (o == 1) ? bk : bv;
            #pragma unroll
            for (int t = 0; t < 4; ++t) {
                float bias = bias_p[t * 16 + m];
                #pragma unroll
                for (int r = 0; r < 4; ++r) {
                    int row = r0 + g * 4 + r;
                    float val = acc[o][t][r] + bias;
                    if (o == 0) {
                        Qo[row * 64 + t * 16 + m] = f2bf(val * QSCALE);
                    } else if (o == 1) {
                        Ko[row * 64 + t * 16 + m] = f2bf(val);
                    } else {
                        int bb = row >> 12, ss = row & 4095;
                        VTo[(size_t)(bb * 64 + t * 16 + m) * SEQ + ss] = f2bf(val);
                    }
                }
            }
        }
    }
}

// ---------------------------------------------------------------------------
// Kernel 2: causal flash attention, 8-way KV split per q-tile.
// New this round: (1) row-sum l computed FREE via a 5th PV accumulator tile
// with constant e0 B-fragment (kills the sum shuffle tree + lrun bookkeeping);
// (2) defer-max with THR=8 (max tree + alpha rescale only on first step /
// rare max growth). P bounded by 2^8 -> fp32/bf16 safe.
// ---------------------------------------------------------------------------
__global__ void __launch_bounds__(512) attn_kernel(
        const unsigned short* __restrict__ Q,
        const unsigned short* __restrict__ K,
        const unsigned short* __restrict__ VT,
        float* __restrict__ out) {
    __shared__ __align__(16) unsigned short P_lds[8][16 * 40];
    __shared__ __align__(16) float pacc[8][16][68];   // pitch 68: 2-way max on writes
    __shared__ float pm[8][16];
    __shared__ float pl[8][16];

    int idx = blockIdx.x;
    int qt = 255 - (idx >> 2);
    int b = idx & 3;
    int q0 = qt * 16;
    int tid = threadIdx.x;
    int w = tid >> 6;
    int lane = tid & 63;
    int m = lane & 15, g = lane >> 4;

    const unsigned short* Qb = Q + (size_t)(b * SEQ + q0 + m) * DOUT + g * 8;
    short8 qf0 = *(const short8*)(Qb);
    short8 qf1 = *(const short8*)(Qb + 32);

    // constant B-fragment e0: column 0 of the 5th tile = all-ones over k
    short8 onesB = (short8){0,0,0,0,0,0,0,0};
    if (m == 0) {
        #pragma unroll
        for (int j = 0; j < 8; ++j) onesB[j] = (short)0x3F80;  // bf16(1.0)
    }

    f32x4 acc[5];
    #pragma unroll
    for (int t = 0; t < 5; ++t) acc[t] = (f32x4){0.f, 0.f, 0.f, 0.f};
    float mrun[4];
    #pragma unroll
    for (int r = 0; r < 4; ++r) mrun[r] = -INFINITY;

    int nsteps = (q0 + 47) >> 5;
    const unsigned short* Kb = K + (size_t)(b * SEQ) * DOUT;
    const unsigned short* Vb = VT + (size_t)(b * DOUT) * SEQ;

    short8 kcur[4];
    if (w < nsteps) {
        int kv0 = w * 32;
        #pragma unroll
        for (int tt = 0; tt < 2; ++tt) {
            const unsigned short* kp = Kb + (size_t)(kv0 + tt * 16 + m) * DOUT + g * 8;
            kcur[tt * 2 + 0] = *(const short8*)(kp);
            kcur[tt * 2 + 1] = *(const short8*)(kp + 32);
        }
    }

    for (int s = w; s < nsteps; s += 8) {
        int kv0 = s * 32;
        short8 vcur[4];
        #pragma unroll
        for (int t = 0; t < 4; ++t)
            vcur[t] = *(const short8*)(Vb + (size_t)(t * 16 + m) * SEQ + kv0 + g * 8);
        short8 knxt[4];
        int sn = s + 8;
        if (sn < nsteps) {
            int kvn = sn * 32;
            #pragma unroll
            for (int tt = 0; tt < 2; ++tt) {
                const unsigned short* kp = Kb + (size_t)(kvn + tt * 16 + m) * DOUT + g * 8;
                knxt[tt * 2 + 0] = *(const short8*)(kp);
                knxt[tt * 2 + 1] = *(const short8*)(kp + 32);
            }
        }

        f32x4 sc[2];
        sc[0] = (f32x4){0.f, 0.f, 0.f, 0.f};
        sc[1] = (f32x4){0.f, 0.f, 0.f, 0.f};
        sc[0] = __builtin_amdgcn_mfma_f32_16x16x32_bf16(qf0, kcur[0], sc[0], 0, 0, 0);
        sc[0] = __builtin_amdgcn_mfma_f32_16x16x32_bf16(qf1, kcur[1], sc[0], 0, 0, 0);
        sc[1] = __builtin_amdgcn_mfma_f32_16x16x32_bf16(qf0, kcur[2], sc[1], 0, 0, 0);
        sc[1] = __builtin_amdgcn_mfma_f32_16x16x32_bf16(qf1, kcur[3], sc[1], 0, 0, 0);

        if (s == nsteps - 1) {
            #pragma unroll
            for (int tt = 0; tt < 2; ++tt)
                #pragma unroll
                for (int r = 0; r < 4; ++r)
                    if (kv0 + tt * 16 + m > q0 + g * 4 + r) sc[tt][r] = -INFINITY;
        }

        // defer-max: full tree + rescale only if some score exceeds mrun + 8
        float th0 = mrun[0] + 8.0f, th1 = mrun[1] + 8.0f;
        float th2 = mrun[2] + 8.0f, th3 = mrun[3] + 8.0f;
        bool need = (sc[0][0] > th0) | (sc[0][1] > th1) | (sc[0][2] > th2) | (sc[0][3] > th3)
                  | (sc[1][0] > th0) | (sc[1][1] > th1) | (sc[1][2] > th2) | (sc[1][3] > th3);
        if (__any(need)) {
            float rmax[4];
            #pragma unroll
            for (int r = 0; r < 4; ++r) rmax[r] = fmaxf(sc[0][r], sc[1][r]);
            #pragma unroll
            for (int msk = 1; msk <= 8; msk <<= 1)
                #pragma unroll
                for (int r = 0; r < 4; ++r)
                    rmax[r] = fmaxf(rmax[r], __shfl_xor(rmax[r], msk));
            #pragma unroll
            for (int r = 0; r < 4; ++r) {
                float mnew = fmaxf(mrun[r], rmax[r]);
                float alpha = __builtin_amdgcn_exp2f(mrun[r] - mnew);  // -inf-finite -> 0
                mrun[r] = mnew;
                #pragma unroll
                for (int t = 0; t < 5; ++t) acc[t][r] *= alpha;
            }
        }

        // P = exp2(sc - mrun), bounded by 2^8
        #pragma unroll
        for (int tt = 0; tt < 2; ++tt)
            #pragma unroll
            for (int r = 0; r < 4; ++r)
                P_lds[w][(g * 4 + r) * 40 + tt * 16 + m] =
                    f2bf(__builtin_amdgcn_exp2f(sc[tt][r] - mrun[r]));
        short8 pa = *(const short8*)&P_lds[w][m * 40 + g * 8];

        #pragma unroll
        for (int t = 0; t < 4; ++t)
            acc[t] = __builtin_amdgcn_mfma_f32_16x16x32_bf16(pa, vcur[t], acc[t], 0, 0, 0);
        acc[4] = __builtin_amdgcn_mfma_f32_16x16x32_bf16(pa, onesB, acc[4], 0, 0, 0);

        if (sn < nsteps) {
            #pragma unroll
            for (int tt = 0; tt < 4; ++tt) kcur[tt] = knxt[tt];
        }
    }

    // per-wave partials: m, l (= acc[4] col 0, lanes m==0), acc
    if (m == 0) {
        #pragma unroll
        for (int r = 0; r < 4; ++r) {
            pm[w][g * 4 + r] = mrun[r];
            pl[w][g * 4 + r] = acc[4][r];
        }
    }
    #pragma unroll
    for (int t = 0; t < 4; ++t)
        #pragma unroll
        for (int r = 0; r < 4; ++r)
            pacc[w][g * 4 + r][t * 16 + m] = acc[t][r];
    __syncthreads();

    // combine: threads 0..255 -> (row, col-quad)
    if (tid < 256) {
        int row = tid >> 4;
        int c4 = (tid & 15) * 4;
        float mmax = pm[0][row];
        #pragma unroll
        for (int w2 = 1; w2 < 8; ++w2) mmax = fmaxf(mmax, pm[w2][row]);
        float lt = 0.f;
        float o0 = 0.f, o1 = 0.f, o2 = 0.f, o3 = 0.f;
        #pragma unroll
        for (int w2 = 0; w2 < 8; ++w2) {
            float sc2 = __builtin_amdgcn_exp2f(pm[w2][row] - mmax);
            lt += pl[w2][row] * sc2;
            const float4 pa4 = *(const float4*)&pacc[w2][row][c4];
            o0 += pa4.x * sc2; o1 += pa4.y * sc2;
            o2 += pa4.z * sc2; o3 += pa4.w * sc2;
        }
        float invl = 1.0f / lt;
        float4 res = make_float4(o0 * invl, o1 * invl, o2 * invl, o3 * invl);
        *(float4*)&out[(size_t)(b * SEQ + q0 + row) * DOUT + c4] = res;
    }
}

// ---------------------------------------------------------------------------
extern "C" void kernel_launch(void* const* d_in, const int* in_sizes, int n_in,
                              void* d_out, int out_size, void* d_ws, size_t ws_size,
                              hipStream_t stream) {
    const float* x  = (const float*)d_in[0];
    const float* wq = (const float*)d_in[1];
    const float* bq = (const float*)d_in[2];
    const float* wk = (const float*)d_in[3];
    const float* bk = (const float*)d_in[4];
    const float* wv = (const float*)d_in[5];
    const float* bv = (const float*)d_in[6];
    float* out = (float*)d_out;

    char* ws = (char*)d_ws;
    unsigned short* wT = (unsigned short*)ws;                       // 294912 B
    unsigned short* Q  = (unsigned short*)(ws + 294912);            // 2 MB
    unsigned short* K  = (unsigned short*)(ws + 294912 + 2097152);  // 2 MB
    unsigned short* VT = (unsigned short*)(ws + 294912 + 4194304);  // 2 MB

    wprep_kernel<<<36, 256, 0, stream>>>(wq, wk, wv, wT);
    proj_kernel<<<1024, 256, 0, stream>>>(x, bq, bk, bv, wT, Q, K, VT);
    attn_kernel<<<1024, 512, 0, stream>>>(Q, K, VT, out);
}

// Round 6
// 128.418 us; speedup vs baseline: 1.4810x; 1.0022x over previous
//
#include <hip/hip_runtime.h>
#include <hip/hip_bf16.h>

#define BATCH 4
#define SEQ   4096
#define DIN   768
#define DOUT  64

typedef __attribute__((ext_vector_type(4))) float f32x4;
typedef __attribute__((ext_vector_type(8))) short short8;

#define QSCALE 0.18033688011112043f  /* 0.125 * log2(e) */

static __device__ __forceinline__ unsigned short f2bf(float f) {
    union { float f; unsigned u; } un; un.f = f;
    unsigned r = un.u + 0x7FFF + ((un.u >> 16) & 1);
    return (unsigned short)(r >> 16);
}

// ---------------------------------------------------------------------------
// Kernel 0: transpose+convert weights: wT[o][n][k] = bf16(w_o[k][n])
// ---------------------------------------------------------------------------
__global__ void wprep_kernel(const float* __restrict__ wq,
                             const float* __restrict__ wk,
                             const float* __restrict__ wv,
                             unsigned short* __restrict__ wT) {
    __shared__ float lds[64][65];
    int o = blockIdx.x / 12, kt = blockIdx.x % 12;
    const float* w = (o == 0) ? wq : (o == 1) ? wk : wv;
    int t = threadIdx.x;
    int k0 = kt * 64;
    #pragma unroll
    for (int i = 0; i < 16; ++i) {
        int flat = t + i * 256;
        int kl = flat >> 6, n = flat & 63;
        lds[kl][n] = w[(k0 + kl) * 64 + n];
    }
    __syncthreads();
    #pragma unroll
    for (int i = 0; i < 16; ++i) {
        int flat = t + i * 256;
        int n = flat >> 6, c = flat & 63;
        wT[(o * 64 + n) * 768 + k0 + c] = f2bf(lds[c][n]);
    }
}

// ---------------------------------------------------------------------------
// Kernel 1: QKV projection, 4-way split-K. (unchanged this round)
// ---------------------------------------------------------------------------
__global__ void __launch_bounds__(256) proj_kernel(
        const float* __restrict__ x,
        const float* __restrict__ bq,
        const float* __restrict__ bk,
        const float* __restrict__ bv,
        const unsigned short* __restrict__ wT,
        unsigned short* __restrict__ Qo,
        unsigned short* __restrict__ Ko,
        unsigned short* __restrict__ VTo) {
    __shared__ float part[3][16][192];
    int tid = threadIdx.x;
    int wv = tid >> 6;
    int lane = tid & 63;
    int m = lane & 15, g = lane >> 4;
    int r0 = blockIdx.x * 16;

    f32x4 acc[3][4];
    #pragma unroll
    for (int o = 0; o < 3; ++o)
        #pragma unroll
        for (int t = 0; t < 4; ++t)
            acc[o][t] = (f32x4){0.f, 0.f, 0.f, 0.f};

    for (int i = 0; i < 6; ++i) {
        int kc = wv + i * 4;
        int k0 = kc * 32 + g * 8;
        const float* xp = x + (size_t)(r0 + m) * DIN + k0;
        float4 lo = *(const float4*)xp;
        float4 hi = *(const float4*)(xp + 4);
        short8 ah;
        ah[0] = (short)f2bf(lo.x); ah[1] = (short)f2bf(lo.y);
        ah[2] = (short)f2bf(lo.z); ah[3] = (short)f2bf(lo.w);
        ah[4] = (short)f2bf(hi.x); ah[5] = (short)f2bf(hi.y);
        ah[6] = (short)f2bf(hi.z); ah[7] = (short)f2bf(hi.w);
        #pragma unroll
        for (int o = 0; o < 3; ++o) {
            #pragma unroll
            for (int t = 0; t < 4; ++t) {
                short8 bfrg = *(const short8*)(wT + (size_t)(o * 64 + t * 16 + m) * DIN + k0);
                acc[o][t] = __builtin_amdgcn_mfma_f32_16x16x32_bf16(ah, bfrg, acc[o][t], 0, 0, 0);
            }
        }
    }

    if (wv > 0) {
        #pragma unroll
        for (int o = 0; o < 3; ++o)
            #pragma unroll
            for (int t = 0; t < 4; ++t)
                #pragma unroll
                for (int r = 0; r < 4; ++r)
                    part[wv - 1][g * 4 + r][o * 64 + t * 16 + m] = acc[o][t][r];
    }
    __syncthreads();
    if (wv == 0) {
        #pragma unroll
        for (int o = 0; o < 3; ++o)
            #pragma unroll
            for (int t = 0; t < 4; ++t)
                #pragma unroll
                for (int r = 0; r < 4; ++r)
                    acc[o][t][r] += part[0][g * 4 + r][o * 64 + t * 16 + m]
                                  + part[1][g * 4 + r][o * 64 + t * 16 + m]
                                  + part[2][g * 4 + r][o * 64 + t * 16 + m];
        #pragma unroll
        for (int o = 0; o < 3; ++o) {
            const float* bias_p = (o == 0) ? bq : (o == 1) ? bk : bv;
            #pragma unroll
            for (int t = 0; t < 4; ++t) {
                float bias = bias_p[t * 16 + m];
                #pragma unroll
                for (int r = 0; r < 4; ++r) {
                    int row = r0 + g * 4 + r;
                    float val = acc[o][t][r] + bias;
                    if (o == 0) {
                        Qo[row * 64 + t * 16 + m] = f2bf(val * QSCALE);
                    } else if (o == 1) {
                        Ko[row * 64 + t * 16 + m] = f2bf(val);
                    } else {
                        int bb = row >> 12, ss = row & 4095;
                        VTo[(size_t)(bb * 64 + t * 16 + m) * SEQ + ss] = f2bf(val);
                    }
                }
            }
        }
    }
}

// ---------------------------------------------------------------------------
// Kernel 2: causal flash attention, 8-way KV split per q-tile.
// New this round: XCD-pinned batch mapping. Blocks round-robin to XCDs by
// blockIdx%8; we map batch b to XCD pair {2b, 2b+1} so each XCD's K/V/Q
// working set is one batch (~1.5 MB) and fits its 4 MB private L2 —
// K/V step loads become L2 hits instead of thrashing to Infinity Cache.
// Longest q-tiles first within each XCD.
// ---------------------------------------------------------------------------
__global__ void __launch_bounds__(512) attn_kernel(
        const unsigned short* __restrict__ Q,
        const unsigned short* __restrict__ K,
        const unsigned short* __restrict__ VT,
        float* __restrict__ out) {
    __shared__ __align__(16) unsigned short P_lds[8][16 * 40];
    __shared__ __align__(16) float pacc[8][16][68];   // pitch 68: 2-way max on writes
    __shared__ float pm[8][16];
    __shared__ float pl[8][16];

    // XCD-pinned remap: xcd = blockIdx%8 (HW round-robin), batch = xcd/2,
    // q-tile walks longest-first per XCD.
    int j = blockIdx.x;
    int xcd = j & 7;
    int round = j >> 3;
    int b = xcd >> 1;
    int qt = 255 - (round * 2 + (xcd & 1));
    int q0 = qt * 16;
    int tid = threadIdx.x;
    int w = tid >> 6;
    int lane = tid & 63;
    int m = lane & 15, g = lane >> 4;

    const unsigned short* Qb = Q + (size_t)(b * SEQ + q0 + m) * DOUT + g * 8;
    short8 qf0 = *(const short8*)(Qb);
    short8 qf1 = *(const short8*)(Qb + 32);

    // constant B-fragment e0: column 0 of the 5th tile = all-ones over k
    short8 onesB = (short8){0,0,0,0,0,0,0,0};
    if (m == 0) {
        #pragma unroll
        for (int j2 = 0; j2 < 8; ++j2) onesB[j2] = (short)0x3F80;  // bf16(1.0)
    }

    f32x4 acc[5];
    #pragma unroll
    for (int t = 0; t < 5; ++t) acc[t] = (f32x4){0.f, 0.f, 0.f, 0.f};
    float mrun[4];
    #pragma unroll
    for (int r = 0; r < 4; ++r) mrun[r] = -INFINITY;

    int nsteps = (q0 + 47) >> 5;
    const unsigned short* Kb = K + (size_t)(b * SEQ) * DOUT;
    const unsigned short* Vb = VT + (size_t)(b * DOUT) * SEQ;

    short8 kcur[4];
    if (w < nsteps) {
        int kv0 = w * 32;
        #pragma unroll
        for (int tt = 0; tt < 2; ++tt) {
            const unsigned short* kp = Kb + (size_t)(kv0 + tt * 16 + m) * DOUT + g * 8;
            kcur[tt * 2 + 0] = *(const short8*)(kp);
            kcur[tt * 2 + 1] = *(const short8*)(kp + 32);
        }
    }

    for (int s = w; s < nsteps; s += 8) {
        int kv0 = s * 32;
        short8 vcur[4];
        #pragma unroll
        for (int t = 0; t < 4; ++t)
            vcur[t] = *(const short8*)(Vb + (size_t)(t * 16 + m) * SEQ + kv0 + g * 8);
        short8 knxt[4];
        int sn = s + 8;
        if (sn < nsteps) {
            int kvn = sn * 32;
            #pragma unroll
            for (int tt = 0; tt < 2; ++tt) {
                const unsigned short* kp = Kb + (size_t)(kvn + tt * 16 + m) * DOUT + g * 8;
                knxt[tt * 2 + 0] = *(const short8*)(kp);
                knxt[tt * 2 + 1] = *(const short8*)(kp + 32);
            }
        }

        f32x4 sc[2];
        sc[0] = (f32x4){0.f, 0.f, 0.f, 0.f};
        sc[1] = (f32x4){0.f, 0.f, 0.f, 0.f};
        sc[0] = __builtin_amdgcn_mfma_f32_16x16x32_bf16(qf0, kcur[0], sc[0], 0, 0, 0);
        sc[0] = __builtin_amdgcn_mfma_f32_16x16x32_bf16(qf1, kcur[1], sc[0], 0, 0, 0);
        sc[1] = __builtin_amdgcn_mfma_f32_16x16x32_bf16(qf0, kcur[2], sc[1], 0, 0, 0);
        sc[1] = __builtin_amdgcn_mfma_f32_16x16x32_bf16(qf1, kcur[3], sc[1], 0, 0, 0);

        if (s == nsteps - 1) {
            #pragma unroll
            for (int tt = 0; tt < 2; ++tt)
                #pragma unroll
                for (int r = 0; r < 4; ++r)
                    if (kv0 + tt * 16 + m > q0 + g * 4 + r) sc[tt][r] = -INFINITY;
        }

        // defer-max: full tree + rescale only if some score exceeds mrun + 8
        float th0 = mrun[0] + 8.0f, th1 = mrun[1] + 8.0f;
        float th2 = mrun[2] + 8.0f, th3 = mrun[3] + 8.0f;
        bool need = (sc[0][0] > th0) | (sc[0][1] > th1) | (sc[0][2] > th2) | (sc[0][3] > th3)
                  | (sc[1][0] > th0) | (sc[1][1] > th1) | (sc[1][2] > th2) | (sc[1][3] > th3);
        if (__any(need)) {
            float rmax[4];
            #pragma unroll
            for (int r = 0; r < 4; ++r) rmax[r] = fmaxf(sc[0][r], sc[1][r]);
            #pragma unroll
            for (int msk = 1; msk <= 8; msk <<= 1)
                #pragma unroll
                for (int r = 0; r < 4; ++r)
                    rmax[r] = fmaxf(rmax[r], __shfl_xor(rmax[r], msk));
            #pragma unroll
            for (int r = 0; r < 4; ++r) {
                float mnew = fmaxf(mrun[r], rmax[r]);
                float alpha = __builtin_amdgcn_exp2f(mrun[r] - mnew);  // -inf-finite -> 0
                mrun[r] = mnew;
                #pragma unroll
                for (int t = 0; t < 5; ++t) acc[t][r] *= alpha;
            }
        }

        // P = exp2(sc - mrun), bounded by 2^8
        #pragma unroll
        for (int tt = 0; tt < 2; ++tt)
            #pragma unroll
            for (int r = 0; r < 4; ++r)
                P_lds[w][(g * 4 + r) * 40 + tt * 16 + m] =
                    f2bf(__builtin_amdgcn_exp2f(sc[tt][r] - mrun[r]));
        short8 pa = *(const short8*)&P_lds[w][m * 40 + g * 8];

        #pragma unroll
        for (int t = 0; t < 4; ++t)
            acc[t] = __builtin_amdgcn_mfma_f32_16x16x32_bf16(pa, vcur[t], acc[t], 0, 0, 0);
        acc[4] = __builtin_amdgcn_mfma_f32_16x16x32_bf16(pa, onesB, acc[4], 0, 0, 0);

        if (sn < nsteps) {
            #pragma unroll
            for (int tt = 0; tt < 4; ++tt) kcur[tt] = knxt[tt];
        }
    }

    // per-wave partials: m, l (= acc[4] col 0, lanes m==0), acc
    if (m == 0) {
        #pragma unroll
        for (int r = 0; r < 4; ++r) {
            pm[w][g * 4 + r] = mrun[r];
            pl[w][g * 4 + r] = acc[4][r];
        }
    }
    #pragma unroll
    for (int t = 0; t < 4; ++t)
        #pragma unroll
        for (int r = 0; r < 4; ++r)
            pacc[w][g * 4 + r][t * 16 + m] = acc[t][r];
    __syncthreads();

    // combine: threads 0..255 -> (row, col-quad)
    if (tid < 256) {
        int row = tid >> 4;
        int c4 = (tid & 15) * 4;
        float mmax = pm[0][row];
        #pragma unroll
        for (int w2 = 1; w2 < 8; ++w2) mmax = fmaxf(mmax, pm[w2][row]);
        float lt = 0.f;
        float o0 = 0.f, o1 = 0.f, o2 = 0.f, o3 = 0.f;
        #pragma unroll
        for (int w2 = 0; w2 < 8; ++w2) {
            float sc2 = __builtin_amdgcn_exp2f(pm[w2][row] - mmax);
            lt += pl[w2][row] * sc2;
            const float4 pa4 = *(const float4*)&pacc[w2][row][c4];
            o0 += pa4.x * sc2; o1 += pa4.y * sc2;
            o2 += pa4.z * sc2; o3 += pa4.w * sc2;
        }
        float invl = 1.0f / lt;
        float4 res = make_float4(o0 * invl, o1 * invl, o2 * invl, o3 * invl);
        *(float4*)&out[(size_t)(b * SEQ + q0 + row) * DOUT + c4] = res;
    }
}

// ---------------------------------------------------------------------------
extern "C" void kernel_launch(void* const* d_in, const int* in_sizes, int n_in,
                              void* d_out, int out_size, void* d_ws, size_t ws_size,
                              hipStream_t stream) {
    const float* x  = (const float*)d_in[0];
    const float* wq = (const float*)d_in[1];
    const float* bq = (const float*)d_in[2];
    const float* wk = (const float*)d_in[3];
    const float* bk = (const float*)d_in[4];
    const float* wv = (const float*)d_in[5];
    const float* bv = (const float*)d_in[6];
    float* out = (float*)d_out;

    char* ws = (char*)d_ws;
    unsigned short* wT = (unsigned short*)ws;                       // 294912 B
    unsigned short* Q  = (unsigned short*)(ws + 294912);            // 2 MB
    unsigned short* K  = (unsigned short*)(ws + 294912 + 2097152);  // 2 MB
    unsigned short* VT = (unsigned short*)(ws + 294912 + 4194304);  // 2 MB

    wprep_kernel<<<36, 256, 0, stream>>>(wq, wk, wv, wT);
    proj_kernel<<<1024, 256, 0, stream>>>(x, bq, bk, bv, wT, Q, K, VT);
    attn_kernel<<<1024, 512, 0, stream>>>(Q, K, VT, out);
}